// Round 1
// baseline (412.127 us; speedup 1.0000x reference)
//
#include <hip/hip_runtime.h>
#include <stdint.h>

static constexpr int KD = 4096;   // inner dim
static constexpr int ND = 4096;   // output features
static constexpr int BK = 128;    // K-bytes per tile step
static constexpr int NT = KD / BK;   // 32 K-tiles

using i32x4 = __attribute__((ext_vector_type(4))) int;

__device__ __forceinline__ void async_copy16(const void* g, void* l) {
    __builtin_amdgcn_global_load_lds(
        (const __attribute__((address_space(1))) void*)g,
        (__attribute__((address_space(3))) void*)l,
        16, 0, 0);
}

// ---------------------------------------------- fused absmax + weight pack --
static constexpr int AB_BLOCKS = 2048;

__global__ __launch_bounds__(256) void prologue_kernel(
        const float* __restrict__ x, unsigned* __restrict__ out_bits, int n4,
        const int* __restrict__ w, int8_t* __restrict__ wq) {
    if (blockIdx.x < AB_BLOCKS) {
        int tid = blockIdx.x * blockDim.x + threadIdx.x;
        int stride = AB_BLOCKS * 256;
        const float4* x4 = (const float4*)x;
        float m0 = 0.f, m1 = 0.f, m2 = 0.f, m3 = 0.f;
        for (int i = tid; i < n4; i += 4 * stride) {
            float4 a = x4[i];
            float4 b = x4[i + stride];
            float4 c = x4[i + 2 * stride];
            float4 d = x4[i + 3 * stride];
            m0 = fmaxf(m0, fmaxf(fmaxf(fabsf(a.x), fabsf(a.y)),
                                 fmaxf(fabsf(a.z), fabsf(a.w))));
            m1 = fmaxf(m1, fmaxf(fmaxf(fabsf(b.x), fabsf(b.y)),
                                 fmaxf(fabsf(b.z), fabsf(b.w))));
            m2 = fmaxf(m2, fmaxf(fmaxf(fabsf(c.x), fabsf(c.y)),
                                 fmaxf(fabsf(c.z), fabsf(c.w))));
            m3 = fmaxf(m3, fmaxf(fmaxf(fabsf(d.x), fabsf(d.y)),
                                 fmaxf(fabsf(d.z), fabsf(d.w))));
        }
        float m = fmaxf(fmaxf(m0, m1), fmaxf(m2, m3));
        #pragma unroll
        for (int off = 32; off > 0; off >>= 1)
            m = fmaxf(m, __shfl_down(m, off, 64));
        __shared__ float wmax[4];
        int lane = threadIdx.x & 63, wv = threadIdx.x >> 6;
        if (lane == 0) wmax[wv] = m;
        __syncthreads();
        if (threadIdx.x == 0) {
            float b = fmaxf(fmaxf(wmax[0], wmax[1]), fmaxf(wmax[2], wmax[3]));
            atomicMax(out_bits, __float_as_uint(b));   // all >=0: bit order ok
        }
    } else {
        int t = (blockIdx.x - AB_BLOCKS) * 256 + threadIdx.x;
        const int4* w4 = (const int4*)(w) + (size_t)t * 4;
        int4 packed;
        int* pp = (int*)&packed;
        #pragma unroll
        for (int g = 0; g < 4; ++g) {
            int4 v = w4[g];
            pp[g] = (v.x & 255) | ((v.y & 255) << 8) |
                    ((v.z & 255) << 16) | (v.w << 24);
        }
        ((int4*)wq)[t] = packed;
    }
}

// ------------------------------------------------------------- quantize x ---
__global__ __launch_bounds__(256) void quant_x_kernel(
        const float* __restrict__ x, const unsigned* __restrict__ mx_bits,
        int8_t* __restrict__ xq) {
    int tid = blockIdx.x * blockDim.x + threadIdx.x;
    float s = __uint_as_float(*mx_bits) / 127.0f;
    float4 v = ((const float4*)x)[tid];
    float t0 = fminf(127.f, fmaxf(-127.f, v.x / s));
    float t1 = fminf(127.f, fmaxf(-127.f, v.y / s));
    float t2 = fminf(127.f, fmaxf(-127.f, v.z / s));
    float t3 = fminf(127.f, fmaxf(-127.f, v.w / s));
    int q0 = (int)t0, q1 = (int)t1, q2 = (int)t2, q3 = (int)t3;
    ((int*)xq)[tid] = (q0 & 255) | ((q1 & 255) << 8) |
                      ((q2 & 255) << 16) | (q3 << 24);
}

// ------------------------------------------------------------------ GEMM ----
// 256x256 tile, BK=128B, 8 waves (2M x 4N), 8-phase schedule (2 K-tiles/iter).
// LDS: [parity][slot] half-slots of 16KB. A slot0 = rows {0-63,128-191},
// slot1 = {64-127,192-255} (so slot0 is only read in phases 0-1, slot1 in
// 2-3). B slot0 = rows 0-127, slot1 = 128-255 (all read in phase 0).
// Staging (tile u, parity p): A(u+1)s1 @ph0 -> p^1 (free since u-1.ph3),
// B(u+2)s0 @ph1 -> p (free since u.ph0), B(u+2)s1 + A(u+2)s0 @ph2 -> p
// (A s0 free since u.ph1). Steady state: vmcnt(6) once per tile at ph3 ==
// 3 half-tiles (6 loads) in flight; freshest needed load has ~4 phases of
// latency cover. No vmcnt(0) in the main loop.
// Swizzle: LDS[row][c] holds global 16B chunk c ^ (row&7); reads are the
// m97/m201-verified conflict-free pattern.

__global__ __launch_bounds__(512, 2) void gemm_i8_kernel(
        const int8_t* __restrict__ Aq,        // M x K
        const int8_t* __restrict__ Wq,        // N x K
        const unsigned* __restrict__ mx_bits,
        const float* __restrict__ wscale_p,
        const float* __restrict__ bias,
        float* __restrict__ out) {
    __shared__ __align__(16) int8_t lds_a[2][32768];
    __shared__ __align__(16) int8_t lds_b[2][32768];

    const int bx = blockIdx.x;                // n tile
    const int by = blockIdx.y;                // m tile
    const int tid  = threadIdx.x;
    const int lane = tid & 63;
    const int w    = tid >> 6;
    const int wm = (w >> 2) * 128;            // wave A-row base (2 groups)
    const int wn = (w & 3) * 64;              // wave B-row base (4 groups)
    const int fr = lane & 15;
    const int kc = lane >> 4;

    // ---- staging addresses: thread t -> slotrow r=t>>3 (and r+64), swizzled
    // global chunk gch = (t&7) ^ (r&7); LDS dest is linear t*16 (+8192).
    const int r   = tid >> 3;                 // 0..63
    const int gch = (tid & 7) ^ (r & 7);
    const int8_t* agp[2][2];
    const int8_t* bgp[2][2];
    #pragma unroll
    for (int s = 0; s < 2; ++s)
        #pragma unroll
        for (int c2 = 0; c2 < 2; ++c2) {
            agp[s][c2] = Aq + (size_t)(by * 256 + r + s * 64 + c2 * 128) * KD
                            + gch * 16;
            bgp[s][c2] = Wq + (size_t)(bx * 256 + r + s * 128 + c2 * 64) * KD
                            + gch * 16;
        }

    // ---- fragment read offsets (within one parity's 32KB region)
    int aoff[8];
    #pragma unroll
    for (int i = 0; i < 8; ++i) {
        int row = wm + i * 16 + fr;
        int s   = (row >> 6) & 1;
        int sr  = (row & 63) | ((row & 128) >> 1);
        aoff[i] = s * 16384 + sr * 128 + ((kc ^ (sr & 7)) << 4);
    }
    int boff[4];
    #pragma unroll
    for (int j = 0; j < 4; ++j) {
        int row = wn + j * 16 + fr;
        int s   = row >> 7;
        int sr  = row & 127;
        boff[j] = s * 16384 + sr * 128 + ((kc ^ (sr & 7)) << 4);
    }

    i32x4 acc[8][4] = {};
    i32x4 bf[4][2];
    i32x4 af[2][2];

#define STG_A(kb, par, s) do { \
    async_copy16(agp[s][0] + (kb), &lds_a[par][(s) * 16384 + tid * 16]); \
    async_copy16(agp[s][1] + (kb), &lds_a[par][(s) * 16384 + tid * 16 + 8192]); \
} while (0)
#define STG_B(kb, par, s) do { \
    async_copy16(bgp[s][0] + (kb), &lds_b[par][(s) * 16384 + tid * 16]); \
    async_copy16(bgp[s][1] + (kb), &lds_b[par][(s) * 16384 + tid * 16 + 8192]); \
} while (0)
#define STG_B2A(kb, par) do { STG_B(kb, par, 1); STG_A(kb, par, 0); } while (0)
#define NOPS ((void)0)
#define VMW6 asm volatile("s_waitcnt vmcnt(6)" ::: "memory")
#define VMW0 asm volatile("s_waitcnt vmcnt(0)" ::: "memory")

#define PHASE(par, q, STAGE, TAIL) do { \
    const int8_t* ab_ = lds_a[par]; \
    const int8_t* bb_ = lds_b[par]; \
    if ((q) == 0) { \
        _Pragma("unroll") \
        for (int jj = 0; jj < 4; ++jj) { \
            bf[jj][0] = *(const i32x4*)(bb_ + boff[jj]); \
            bf[jj][1] = *(const i32x4*)(bb_ + (boff[jj] ^ 64)); \
        } \
    } \
    af[0][0] = *(const i32x4*)(ab_ + aoff[2 * (q)]); \
    af[0][1] = *(const i32x4*)(ab_ + (aoff[2 * (q)] ^ 64)); \
    af[1][0] = *(const i32x4*)(ab_ + aoff[2 * (q) + 1]); \
    af[1][1] = *(const i32x4*)(ab_ + (aoff[2 * (q) + 1] ^ 64)); \
    STAGE; \
    __builtin_amdgcn_s_barrier(); \
    asm volatile("s_waitcnt lgkmcnt(0)"); \
    __builtin_amdgcn_sched_barrier(0); \
    __builtin_amdgcn_s_setprio(1); \
    _Pragma("unroll") \
    for (int ss = 0; ss < 2; ++ss) \
        _Pragma("unroll") \
        for (int jj = 0; jj < 4; ++jj) \
            _Pragma("unroll") \
            for (int ii = 0; ii < 2; ++ii) \
                acc[2 * (q) + ii][jj] = __builtin_amdgcn_mfma_i32_16x16x64_i8( \
                    af[ii][ss], bf[jj][ss], acc[2 * (q) + ii][jj], 0, 0, 0); \
    __builtin_amdgcn_s_setprio(0); \
    TAIL; \
    __builtin_amdgcn_s_barrier(); \
} while (0)

#define TILE_STEADY(par, u) do { \
    const int kb1 = ((u) + 1) * BK; \
    const int kb2 = ((u) + 2) * BK; \
    PHASE(par, 0, STG_A(kb1, (par) ^ 1, 1), NOPS); \
    PHASE(par, 1, STG_B(kb2, par, 0), NOPS); \
    PHASE(par, 2, STG_B2A(kb2, par), NOPS); \
    PHASE(par, 3, NOPS, VMW6); \
} while (0)

    // ---- prologue: tile 0 fully + {B(1)s0, B(1)s1, A(1)s0} in flight
    STG_A(0, 0, 0); STG_A(0, 0, 1); STG_B(0, 0, 0); STG_B(0, 0, 1);
    STG_B(BK, 1, 0); STG_B(BK, 1, 1); STG_A(BK, 1, 0);
    VMW6;
    __builtin_amdgcn_s_barrier();

    // ---- main loop: tiles 0..29 (staging refs tiles <= 31, always valid)
    #pragma unroll 1
    for (int it = 0; it < 15; ++it) {
        const int u0 = 2 * it;
        TILE_STEADY(0, u0);
        TILE_STEADY(1, u0 + 1);
    }

    // ---- tail: tile 30 (stages only A(31)s1; drain), tile 31 (compute only)
    PHASE(0, 0, STG_A(31 * BK, 1, 1), NOPS);
    PHASE(0, 1, NOPS, NOPS);
    PHASE(0, 2, NOPS, NOPS);
    PHASE(0, 3, NOPS, VMW0);
    PHASE(1, 0, NOPS, NOPS);
    PHASE(1, 1, NOPS, NOPS);
    PHASE(1, 2, NOPS, NOPS);
    PHASE(1, 3, NOPS, NOPS);

    // ---- epilogue
    const float stot = (__uint_as_float(*mx_bits) / 127.0f) * (*wscale_p);
    float bj[4];
    #pragma unroll
    for (int j = 0; j < 4; ++j)
        bj[j] = bias[bx * 256 + wn + j * 16 + fr];

    #pragma unroll
    for (int i = 0; i < 8; ++i) {
        int mrow = by * 256 + wm + i * 16 + kc * 4;    // + reg index rr
        #pragma unroll
        for (int rr = 0; rr < 4; ++rr) {
            float* orow = out + (size_t)(mrow + rr) * ND + bx * 256;
            #pragma unroll
            for (int j = 0; j < 4; ++j)
                orow[wn + j * 16 + fr] = (float)acc[i][j][rr] * stot + bj[j];
        }
    }
}

// ---------------------------------------------------------------- launch ----
extern "C" void kernel_launch(void* const* d_in, const int* in_sizes, int n_in,
                              void* d_out, int out_size, void* d_ws, size_t ws_size,
                              hipStream_t stream) {
    const float* x      = (const float*)d_in[0];
    const int*   wgt    = (const int*)d_in[1];     // int8 values widened to i32
    const float* wscale = (const float*)d_in[2];
    const float* bias   = (const float*)d_in[3];
    float* out = (float*)d_out;

    const int M = in_sizes[0] / KD;                // 8192

    uint8_t* ws = (uint8_t*)d_ws;
    unsigned* mx_bits = (unsigned*)ws;
    int8_t* xq = (int8_t*)(ws + 256);
    int8_t* wq = (int8_t*)(ws + 256 + (size_t)M * KD);

    const int pk_blocks = (ND * KD / 16) / 256;    // 4096
    hipMemsetAsync(mx_bits, 0, 4, stream);
    prologue_kernel<<<AB_BLOCKS + pk_blocks, 256, 0, stream>>>(
        x, mx_bits, (M * KD) / 4, wgt, wq);
    quant_x_kernel<<<(M * KD / 4) / 256, 256, 0, stream>>>(x, mx_bits, xq);
    gemm_i8_kernel<<<dim3(ND / 256, M / 256), 512, 0, stream>>>(
        xq, wq, mx_bits, wscale, bias, out);
}

// Round 2
// 408.728 us; speedup vs baseline: 1.0083x; 1.0083x over previous
//
#include <hip/hip_runtime.h>
#include <stdint.h>

static constexpr int KD = 4096;   // inner dim
static constexpr int ND = 4096;   // output features
static constexpr int BK = 128;    // K-bytes per tile step

using i32x4 = __attribute__((ext_vector_type(4))) int;

__device__ __forceinline__ void async_copy16(const void* g, void* l) {
    __builtin_amdgcn_global_load_lds(
        (const __attribute__((address_space(1))) void*)g,
        (__attribute__((address_space(3))) void*)l,
        16, 0, 0);
}

// LDS byte offset of a __shared__ pointer (AS3 ptr == raw LDS offset).
__device__ __forceinline__ uint32_t lds_addr(const void* p) {
    return (uint32_t)(uintptr_t)(__attribute__((address_space(3))) const void*)p;
}

// Inline-asm ds_read_b128: opaque to SIInsertWaitcnts, so the compiler cannot
// inject conservative vmcnt waits for outstanding global_load_lds DMA (the
// round-1 MfmaUtil=41% theory).  Manual lgkmcnt(0)+sched_barrier(0) before the
// MFMA cluster is the required fence (rule #18).
template<int IMM>
__device__ __forceinline__ i32x4 dsr(uint32_t a) {
    i32x4 d;
    if constexpr (IMM == 0)
        asm volatile("ds_read_b128 %0, %1" : "=v"(d) : "v"(a));
    else
        asm volatile("ds_read_b128 %0, %1 offset:%2" : "=v"(d) : "v"(a), "n"(IMM));
    return d;
}

// ---------------------------------------------- fused absmax + weight pack --
static constexpr int AB_BLOCKS = 2048;

__global__ __launch_bounds__(256) void prologue_kernel(
        const float* __restrict__ x, unsigned* __restrict__ out_bits, int n4,
        const int* __restrict__ w, int8_t* __restrict__ wq) {
    if (blockIdx.x < AB_BLOCKS) {
        int tid = blockIdx.x * blockDim.x + threadIdx.x;
        int stride = AB_BLOCKS * 256;
        const float4* x4 = (const float4*)x;
        float m0 = 0.f, m1 = 0.f, m2 = 0.f, m3 = 0.f;
        for (int i = tid; i < n4; i += 4 * stride) {
            float4 a = x4[i];
            float4 b = x4[i + stride];
            float4 c = x4[i + 2 * stride];
            float4 d = x4[i + 3 * stride];
            m0 = fmaxf(m0, fmaxf(fmaxf(fabsf(a.x), fabsf(a.y)),
                                 fmaxf(fabsf(a.z), fabsf(a.w))));
            m1 = fmaxf(m1, fmaxf(fmaxf(fabsf(b.x), fabsf(b.y)),
                                 fmaxf(fabsf(b.z), fabsf(b.w))));
            m2 = fmaxf(m2, fmaxf(fmaxf(fabsf(c.x), fabsf(c.y)),
                                 fmaxf(fabsf(c.z), fabsf(c.w))));
            m3 = fmaxf(m3, fmaxf(fmaxf(fabsf(d.x), fabsf(d.y)),
                                 fmaxf(fabsf(d.z), fabsf(d.w))));
        }
        float m = fmaxf(fmaxf(m0, m1), fmaxf(m2, m3));
        #pragma unroll
        for (int off = 32; off > 0; off >>= 1)
            m = fmaxf(m, __shfl_down(m, off, 64));
        __shared__ float wmax[4];
        int lane = threadIdx.x & 63, wv = threadIdx.x >> 6;
        if (lane == 0) wmax[wv] = m;
        __syncthreads();
        if (threadIdx.x == 0) {
            float b = fmaxf(fmaxf(wmax[0], wmax[1]), fmaxf(wmax[2], wmax[3]));
            atomicMax(out_bits, __float_as_uint(b));   // all >=0: bit order ok
        }
    } else {
        int t = (blockIdx.x - AB_BLOCKS) * 256 + threadIdx.x;
        const int4* w4 = (const int4*)(w) + (size_t)t * 4;
        int4 packed;
        int* pp = (int*)&packed;
        #pragma unroll
        for (int g = 0; g < 4; ++g) {
            int4 v = w4[g];
            pp[g] = (v.x & 255) | ((v.y & 255) << 8) |
                    ((v.z & 255) << 16) | (v.w << 24);
        }
        ((int4*)wq)[t] = packed;
    }
}

// ------------------------------------------------------------- quantize x ---
__global__ __launch_bounds__(256) void quant_x_kernel(
        const float* __restrict__ x, const unsigned* __restrict__ mx_bits,
        int8_t* __restrict__ xq) {
    int tid = blockIdx.x * blockDim.x + threadIdx.x;
    float s = __uint_as_float(*mx_bits) / 127.0f;
    float4 v = ((const float4*)x)[tid];
    float t0 = fminf(127.f, fmaxf(-127.f, v.x / s));
    float t1 = fminf(127.f, fmaxf(-127.f, v.y / s));
    float t2 = fminf(127.f, fmaxf(-127.f, v.z / s));
    float t3 = fminf(127.f, fmaxf(-127.f, v.w / s));
    int q0 = (int)t0, q1 = (int)t1, q2 = (int)t2, q3 = (int)t3;
    ((int*)xq)[tid] = (q0 & 255) | ((q1 & 255) << 8) |
                      ((q2 & 255) << 16) | (q3 << 24);
}

// ------------------------------------------------------------------ GEMM ----
// 256x256 tile, BK=128B, 8 waves (2M x 4N), 8-phase schedule (2 K-tiles/iter).
// Slot/staging/vmcnt discipline identical to round 1 (induction-verified:
// carry-in invariant 6 outstanding loads; vmcnt(6) at ph3 retires exactly the
// next tile's 8 loads; every DMA target's last reader retired >=1 barrier
// before the DMA issue).  Round-2 changes: (a) fragment reads are inline-asm
// ds_read_b128 so no compiler-inserted vmcnt drains; (b) XCD-aware block
// swizzle (512 blocks, 512%8==0 -> simple bijective form).
__global__ __launch_bounds__(512, 2) void gemm_i8_kernel(
        const int8_t* __restrict__ Aq,        // M x K
        const int8_t* __restrict__ Wq,        // N x K
        const unsigned* __restrict__ mx_bits,
        const float* __restrict__ wscale_p,
        const float* __restrict__ bias,
        float* __restrict__ out) {
    __shared__ __align__(16) int8_t lds_a[2][32768];
    __shared__ __align__(16) int8_t lds_b[2][32768];

    // ---- XCD swizzle: consecutive hw block ids round-robin XCDs; remap so
    // each XCD owns 64 consecutive logical tiles (= 4 full by-rows).
    const int fid = blockIdx.y * gridDim.x + blockIdx.x;   // 0..511
    const int swz = (fid & 7) * 64 + (fid >> 3);
    const int bx = swz & 15;                  // n tile (ND/256 = 16)
    const int by = swz >> 4;                  // m tile

    const int tid  = threadIdx.x;
    const int lane = tid & 63;
    const int w    = tid >> 6;
    const int wm = (w >> 2) * 128;            // wave A-row base (2 groups)
    const int wn = (w & 3) * 64;              // wave B-row base (4 groups)
    const int fr = lane & 15;
    const int kc = lane >> 4;

    // ---- staging addresses: thread t -> slotrow r=t>>3 (and r+64), swizzled
    // global chunk gch = (t&7) ^ (r&7); LDS dest is linear t*16 (+8192).
    const int r   = tid >> 3;                 // 0..63
    const int gch = (tid & 7) ^ (r & 7);
    const int8_t* agp[2][2];
    const int8_t* bgp[2][2];
    #pragma unroll
    for (int s = 0; s < 2; ++s)
        #pragma unroll
        for (int c2 = 0; c2 < 2; ++c2) {
            agp[s][c2] = Aq + (size_t)(by * 256 + r + s * 64 + c2 * 128) * KD
                            + gch * 16;
            bgp[s][c2] = Wq + (size_t)(bx * 256 + r + s * 128 + c2 * 64) * KD
                            + gch * 16;
        }

    // ---- fragment read addresses (parity-0 region; parity 1 = offset:32768)
    const uint32_t Abase = lds_addr(&lds_a[0][0]);
    const uint32_t Bbase = lds_addr(&lds_b[0][0]);
    uint32_t aofs[8];
    #pragma unroll
    for (int i = 0; i < 8; ++i) {
        int row = wm + i * 16 + fr;
        int s   = (row >> 6) & 1;
        int sr  = (row & 63) | ((row & 128) >> 1);
        aofs[i] = Abase + s * 16384 + sr * 128 + ((kc ^ (sr & 7)) << 4);
    }
    uint32_t bofs[4];
    #pragma unroll
    for (int j = 0; j < 4; ++j) {
        int row = wn + j * 16 + fr;
        int s   = row >> 7;
        int sr  = row & 127;
        bofs[j] = Bbase + s * 16384 + sr * 128 + ((kc ^ (sr & 7)) << 4);
    }

    i32x4 acc[8][4] = {};
    i32x4 bf[4][2];
    i32x4 af[2][2];

#define STG_A(kb, par, s) do { \
    async_copy16(agp[s][0] + (kb), &lds_a[par][(s) * 16384 + tid * 16]); \
    async_copy16(agp[s][1] + (kb), &lds_a[par][(s) * 16384 + tid * 16 + 8192]); \
} while (0)
#define STG_B(kb, par, s) do { \
    async_copy16(bgp[s][0] + (kb), &lds_b[par][(s) * 16384 + tid * 16]); \
    async_copy16(bgp[s][1] + (kb), &lds_b[par][(s) * 16384 + tid * 16 + 8192]); \
} while (0)
#define STG_B2A(kb, par) do { STG_B(kb, par, 1); STG_A(kb, par, 0); } while (0)
#define NOPS ((void)0)
#define VMW6 asm volatile("s_waitcnt vmcnt(6)" ::: "memory")
#define VMW0 asm volatile("s_waitcnt vmcnt(0)" ::: "memory")

#define PHASE(par, q, STAGE, TAIL) do { \
    if ((q) == 0) { \
        _Pragma("unroll") \
        for (int jj = 0; jj < 4; ++jj) { \
            bf[jj][0] = dsr<(par) * 32768>(bofs[jj]); \
            bf[jj][1] = dsr<(par) * 32768>(bofs[jj] ^ 64u); \
        } \
    } \
    af[0][0] = dsr<(par) * 32768>(aofs[2 * (q)]); \
    af[0][1] = dsr<(par) * 32768>(aofs[2 * (q)] ^ 64u); \
    af[1][0] = dsr<(par) * 32768>(aofs[2 * (q) + 1]); \
    af[1][1] = dsr<(par) * 32768>(aofs[2 * (q) + 1] ^ 64u); \
    STAGE; \
    __builtin_amdgcn_s_barrier(); \
    asm volatile("s_waitcnt lgkmcnt(0)" ::: "memory"); \
    __builtin_amdgcn_sched_barrier(0); \
    __builtin_amdgcn_s_setprio(1); \
    _Pragma("unroll") \
    for (int ss = 0; ss < 2; ++ss) \
        _Pragma("unroll") \
        for (int jj = 0; jj < 4; ++jj) \
            _Pragma("unroll") \
            for (int ii = 0; ii < 2; ++ii) \
                acc[2 * (q) + ii][jj] = __builtin_amdgcn_mfma_i32_16x16x64_i8( \
                    af[ii][ss], bf[jj][ss], acc[2 * (q) + ii][jj], 0, 0, 0); \
    __builtin_amdgcn_s_setprio(0); \
    TAIL; \
    __builtin_amdgcn_s_barrier(); \
} while (0)

#define TILE_STEADY(par, u) do { \
    const int kb1 = ((u) + 1) * BK; \
    const int kb2 = ((u) + 2) * BK; \
    PHASE(par, 0, STG_A(kb1, (par) ^ 1, 1), NOPS); \
    PHASE(par, 1, STG_B(kb2, par, 0), NOPS); \
    PHASE(par, 2, STG_B2A(kb2, par), NOPS); \
    PHASE(par, 3, NOPS, VMW6); \
} while (0)

    // ---- prologue: tile 0 fully + {B(1)s0, B(1)s1, A(1)s0} in flight
    STG_A(0, 0, 0); STG_A(0, 0, 1); STG_B(0, 0, 0); STG_B(0, 0, 1);
    STG_B(BK, 1, 0); STG_B(BK, 1, 1); STG_A(BK, 1, 0);
    VMW6;
    __builtin_amdgcn_s_barrier();

    // ---- main loop: tiles 0..29 (staging refs tiles <= 31, always valid)
    #pragma unroll 1
    for (int it = 0; it < 15; ++it) {
        const int u0 = 2 * it;
        TILE_STEADY(0, u0);
        TILE_STEADY(1, u0 + 1);
    }

    // ---- tail: tile 30 (stages only A(31)s1; drain), tile 31 (compute only)
    PHASE(0, 0, STG_A(31 * BK, 1, 1), NOPS);
    PHASE(0, 1, NOPS, NOPS);
    PHASE(0, 2, NOPS, NOPS);
    PHASE(0, 3, NOPS, VMW0);
    PHASE(1, 0, NOPS, NOPS);
    PHASE(1, 1, NOPS, NOPS);
    PHASE(1, 2, NOPS, NOPS);
    PHASE(1, 3, NOPS, NOPS);

    // ---- epilogue
    const float stot = (__uint_as_float(*mx_bits) / 127.0f) * (*wscale_p);
    float bj[4];
    #pragma unroll
    for (int j = 0; j < 4; ++j)
        bj[j] = bias[bx * 256 + wn + j * 16 + fr];

    #pragma unroll
    for (int i = 0; i < 8; ++i) {
        int mrow = by * 256 + wm + i * 16 + kc * 4;    // + reg index rr
        #pragma unroll
        for (int rr = 0; rr < 4; ++rr) {
            float* orow = out + (size_t)(mrow + rr) * ND + bx * 256;
            #pragma unroll
            for (int j = 0; j < 4; ++j)
                orow[wn + j * 16 + fr] = (float)acc[i][j][rr] * stot + bj[j];
        }
    }
}

// ---------------------------------------------------------------- launch ----
extern "C" void kernel_launch(void* const* d_in, const int* in_sizes, int n_in,
                              void* d_out, int out_size, void* d_ws, size_t ws_size,
                              hipStream_t stream) {
    const float* x      = (const float*)d_in[0];
    const int*   wgt    = (const int*)d_in[1];     // int8 values widened to i32
    const float* wscale = (const float*)d_in[2];
    const float* bias   = (const float*)d_in[3];
    float* out = (float*)d_out;

    const int M = in_sizes[0] / KD;                // 8192

    uint8_t* ws = (uint8_t*)d_ws;
    unsigned* mx_bits = (unsigned*)ws;
    int8_t* xq = (int8_t*)(ws + 256);
    int8_t* wq = (int8_t*)(ws + 256 + (size_t)M * KD);

    const int pk_blocks = (ND * KD / 16) / 256;    // 4096
    hipMemsetAsync(mx_bits, 0, 4, stream);
    prologue_kernel<<<AB_BLOCKS + pk_blocks, 256, 0, stream>>>(
        x, mx_bits, (M * KD) / 4, wgt, wq);
    quant_x_kernel<<<(M * KD / 4) / 256, 256, 0, stream>>>(x, mx_bits, xq);
    gemm_i8_kernel<<<dim3(ND / 256, M / 256), 512, 0, stream>>>(
        xq, wq, mx_bits, wscale, bias, out);
}

// Round 5
// 407.730 us; speedup vs baseline: 1.0108x; 1.0024x over previous
//
#include <hip/hip_runtime.h>
#include <stdint.h>

static constexpr int KD = 4096;   // inner dim
static constexpr int ND = 4096;   // output features
static constexpr int BK = 128;    // K-bytes per tile step

using i32x4 = __attribute__((ext_vector_type(4))) int;

__device__ __forceinline__ void async_copy16(const void* g, void* l) {
    __builtin_amdgcn_global_load_lds(
        (const __attribute__((address_space(1))) void*)g,
        (__attribute__((address_space(3))) void*)l,
        16, 0, 0);
}

__device__ __forceinline__ uint32_t lds_addr(const void* p) {
    return (uint32_t)(uintptr_t)(__attribute__((address_space(3))) const void*)p;
}

// Inline-asm ds_read_b128 (opaque to SIInsertWaitcnts; manual counted lgkmcnt
// + sched_barrier(0) is the fence, rule #18).
template<int IMM>
__device__ __forceinline__ i32x4 dsr(uint32_t a) {
    i32x4 d;
    if constexpr (IMM == 0)
        asm volatile("ds_read_b128 %0, %1" : "=v"(d) : "v"(a));
    else
        asm volatile("ds_read_b128 %0, %1 offset:%2" : "=v"(d) : "v"(a), "n"(IMM));
    return d;
}

// ---------------------------------------------- fused absmax + weight pack --
static constexpr int AB_BLOCKS = 2048;

__global__ __launch_bounds__(256) void prologue_kernel(
        const float* __restrict__ x, unsigned* __restrict__ out_bits, int n4,
        const int* __restrict__ w, int8_t* __restrict__ wq) {
    if (blockIdx.x < AB_BLOCKS) {
        int tid = blockIdx.x * blockDim.x + threadIdx.x;
        int stride = AB_BLOCKS * 256;
        const float4* x4 = (const float4*)x;
        float m0 = 0.f, m1 = 0.f, m2 = 0.f, m3 = 0.f;
        for (int i = tid; i < n4; i += 4 * stride) {
            float4 a = x4[i];
            float4 b = x4[i + stride];
            float4 c = x4[i + 2 * stride];
            float4 d = x4[i + 3 * stride];
            m0 = fmaxf(m0, fmaxf(fmaxf(fabsf(a.x), fabsf(a.y)),
                                 fmaxf(fabsf(a.z), fabsf(a.w))));
            m1 = fmaxf(m1, fmaxf(fmaxf(fabsf(b.x), fabsf(b.y)),
                                 fmaxf(fabsf(b.z), fabsf(b.w))));
            m2 = fmaxf(m2, fmaxf(fmaxf(fabsf(c.x), fabsf(c.y)),
                                 fmaxf(fabsf(c.z), fabsf(c.w))));
            m3 = fmaxf(m3, fmaxf(fmaxf(fabsf(d.x), fabsf(d.y)),
                                 fmaxf(fabsf(d.z), fabsf(d.w))));
        }
        float m = fmaxf(fmaxf(m0, m1), fmaxf(m2, m3));
        #pragma unroll
        for (int off = 32; off > 0; off >>= 1)
            m = fmaxf(m, __shfl_down(m, off, 64));
        __shared__ float wmax[4];
        int lane = threadIdx.x & 63, wv = threadIdx.x >> 6;
        if (lane == 0) wmax[wv] = m;
        __syncthreads();
        if (threadIdx.x == 0) {
            float b = fmaxf(fmaxf(wmax[0], wmax[1]), fmaxf(wmax[2], wmax[3]));
            atomicMax(out_bits, __float_as_uint(b));   // all >=0: bit order ok
        }
    } else {
        int t = (blockIdx.x - AB_BLOCKS) * 256 + threadIdx.x;
        const int4* w4 = (const int4*)(w) + (size_t)t * 4;
        int4 packed;
        int* pp = (int*)&packed;
        #pragma unroll
        for (int g = 0; g < 4; ++g) {
            int4 v = w4[g];
            pp[g] = (v.x & 255) | ((v.y & 255) << 8) |
                    ((v.z & 255) << 16) | (v.w << 24);
        }
        ((int4*)wq)[t] = packed;
    }
}

// ------------------------------------------------------------- quantize x ---
// Round-5 rewrite: mirror absmax's proven streaming shape (2048 blocks,
// grid-stride, 4 independent loads in flight per iteration) instead of
// 1 load + 1 store per thread.  Math is bit-identical to the reference
// (IEEE div, clip to +-127, trunc-to-zero).
__global__ __launch_bounds__(256) void quant_x_kernel(
        const float* __restrict__ x, const unsigned* __restrict__ mx_bits,
        int8_t* __restrict__ xq, int n4) {
    const int tid = blockIdx.x * blockDim.x + threadIdx.x;
    const int stride = AB_BLOCKS * 256;
    const float s = __uint_as_float(*mx_bits) / 127.0f;
    const float4* x4 = (const float4*)x;
    int* q4 = (int*)xq;
    for (int i = tid; i < n4; i += 4 * stride) {
        float4 v0 = x4[i];
        float4 v1 = x4[i + stride];
        float4 v2 = x4[i + 2 * stride];
        float4 v3 = x4[i + 3 * stride];
        #pragma unroll
        for (int g = 0; g < 4; ++g) {
            float4 v = g == 0 ? v0 : g == 1 ? v1 : g == 2 ? v2 : v3;
            float t0 = fminf(127.f, fmaxf(-127.f, v.x / s));
            float t1 = fminf(127.f, fmaxf(-127.f, v.y / s));
            float t2 = fminf(127.f, fmaxf(-127.f, v.z / s));
            float t3 = fminf(127.f, fmaxf(-127.f, v.w / s));
            int q0 = (int)t0, q1 = (int)t1, q2 = (int)t2, q3 = (int)t3;
            q4[i + g * stride] = (q0 & 255) | ((q1 & 255) << 8) |
                                 ((q2 & 255) << 16) | (q3 << 24);
        }
    }
}

// ------------------------------------------------------------------ GEMM ----
// 256x256 tile, BK=128B, 8 waves (2M x 4N), 4 phases/tile, ONE barrier/phase.
// A-fragments prefetched one phase ahead (afX/afY ping-pong, counted
// lgkmcnt(4)); ph0's B reads drain under the first 8-MFMA batch (lgkmcnt(8) /
// lgkmcnt(4) ss-split); pre-MFMA barrier removed (hazard audit: only
// phase-END barriers order read-drain vs DMA overwrite).
// Staging (tile u, parity p): A(u+1)s1 @ph0 -> p^1; B(u+2)s0 @ph1 -> p;
// B(u+2)s1+A(u+2)s0 @ph2 -> p.  vmcnt TAILs: ph0:6, ph1:4, ph2:6, ph3:none.
// FIFO induction: entering tile u, 6 outstanding {B(u+1)s0,B(u+1)s1,A(u+1)s0};
// ph0 VMW(6) retires B(u+1)s0, ph1 VMW(4) retires B(u+1)s1+A(u+1)s0, ph2
// VMW(6) retires A(u+1)s1 -> tile u+1 complete at ph2-end barrier; every DMA
// has >=2 phases (~1300cy) of latency cover.  Hang/fault audit (round 4):
// uniform branch-free barriers, satisfiable waits, all addresses bounded.
__global__ __launch_bounds__(512, 2) void gemm_i8_kernel(
        const int8_t* __restrict__ Aq,        // M x K
        const int8_t* __restrict__ Wq,        // N x K
        const unsigned* __restrict__ mx_bits,
        const float* __restrict__ wscale_p,
        const float* __restrict__ bias,
        float* __restrict__ out) {
    __shared__ __align__(16) int8_t lds_a[2][32768];
    __shared__ __align__(16) int8_t lds_b[2][32768];

    // ---- XCD swizzle (512 blocks, bijective): each XCD owns 4 full by-rows.
    const int fid = blockIdx.y * gridDim.x + blockIdx.x;   // 0..511
    const int swz = (fid & 7) * 64 + (fid >> 3);
    const int bx = swz & 15;                  // n tile (ND/256 = 16)
    const int by = swz >> 4;                  // m tile

    const int tid  = threadIdx.x;
    const int lane = tid & 63;
    const int w    = tid >> 6;
    const int wm = (w >> 2) * 128;            // wave A-row base (2 groups)
    const int wn = (w & 3) * 64;              // wave B-row base (4 groups)
    const int fr = lane & 15;
    const int kc = lane >> 4;

    // ---- staging addresses: thread t -> slotrow r=t>>3 (and r+64), swizzled
    // global chunk gch = (t&7) ^ (r&7); LDS dest linear t*16 (+8192).
    const int r   = tid >> 3;                 // 0..63
    const int gch = (tid & 7) ^ (r & 7);
    const int8_t* agp[2][2];
    const int8_t* bgp[2][2];
    #pragma unroll
    for (int s = 0; s < 2; ++s)
        #pragma unroll
        for (int c2 = 0; c2 < 2; ++c2) {
            agp[s][c2] = Aq + (size_t)(by * 256 + r + s * 64 + c2 * 128) * KD
                            + gch * 16;
            bgp[s][c2] = Wq + (size_t)(bx * 256 + r + s * 128 + c2 * 64) * KD
                            + gch * 16;
        }

    // ---- fragment read addresses (parity-0 region; parity 1 = offset:32768)
    const uint32_t Abase = lds_addr(&lds_a[0][0]);
    const uint32_t Bbase = lds_addr(&lds_b[0][0]);
    uint32_t aofs[8];
    #pragma unroll
    for (int i = 0; i < 8; ++i) {
        int row = wm + i * 16 + fr;
        int s   = (row >> 6) & 1;
        int sr  = (row & 63) | ((row & 128) >> 1);
        aofs[i] = Abase + s * 16384 + sr * 128 + ((kc ^ (sr & 7)) << 4);
    }
    uint32_t bofs[4];
    #pragma unroll
    for (int j = 0; j < 4; ++j) {
        int row = wn + j * 16 + fr;
        int s   = row >> 7;
        int sr  = row & 127;
        bofs[j] = Bbase + s * 16384 + sr * 128 + ((kc ^ (sr & 7)) << 4);
    }

    i32x4 acc[8][4] = {};
    i32x4 bf[4][2];
    i32x4 afX[2][2];
    i32x4 afY[2][2];

#define STG_A(kb, par, s) do { \
    async_copy16(agp[s][0] + (kb), &lds_a[par][(s) * 16384 + tid * 16]); \
    async_copy16(agp[s][1] + (kb), &lds_a[par][(s) * 16384 + tid * 16 + 8192]); \
} while (0)
#define STG_B(kb, par, s) do { \
    async_copy16(bgp[s][0] + (kb), &lds_b[par][(s) * 16384 + tid * 16]); \
    async_copy16(bgp[s][1] + (kb), &lds_b[par][(s) * 16384 + tid * 16 + 8192]); \
} while (0)
#define STG_B2A(kb, par) do { STG_B(kb, par, 1); STG_A(kb, par, 0); } while (0)
#define NOPS ((void)0)
#define VMW(N) asm volatile("s_waitcnt vmcnt(" #N ")" ::: "memory")
#define LGKM(N) do { \
    asm volatile("s_waitcnt lgkmcnt(" #N ")" ::: "memory"); \
    __builtin_amdgcn_sched_barrier(0); \
} while (0)
#define BAR __builtin_amdgcn_s_barrier()

#define RD_AF(DST, I0, PAR) do { \
    DST[0][0] = dsr<(PAR) * 32768>(aofs[I0]); \
    DST[0][1] = dsr<(PAR) * 32768>(aofs[I0] ^ 64u); \
    DST[1][0] = dsr<(PAR) * 32768>(aofs[(I0) + 1]); \
    DST[1][1] = dsr<(PAR) * 32768>(aofs[(I0) + 1] ^ 64u); \
} while (0)
#define RD_BF(PAR) do { \
    bf[0][0] = dsr<(PAR) * 32768>(bofs[0]); \
    bf[1][0] = dsr<(PAR) * 32768>(bofs[1]); \
    bf[2][0] = dsr<(PAR) * 32768>(bofs[2]); \
    bf[3][0] = dsr<(PAR) * 32768>(bofs[3]); \
    bf[0][1] = dsr<(PAR) * 32768>(bofs[0] ^ 64u); \
    bf[1][1] = dsr<(PAR) * 32768>(bofs[1] ^ 64u); \
    bf[2][1] = dsr<(PAR) * 32768>(bofs[2] ^ 64u); \
    bf[3][1] = dsr<(PAR) * 32768>(bofs[3] ^ 64u); \
} while (0)

#define MFMA8(Q, AF, SS) do { \
    _Pragma("unroll") \
    for (int jj = 0; jj < 4; ++jj) { \
        acc[2 * (Q)][jj] = __builtin_amdgcn_mfma_i32_16x16x64_i8( \
            AF[0][SS], bf[jj][SS], acc[2 * (Q)][jj], 0, 0, 0); \
        acc[2 * (Q) + 1][jj] = __builtin_amdgcn_mfma_i32_16x16x64_i8( \
            AF[1][SS], bf[jj][SS], acc[2 * (Q) + 1][jj], 0, 0, 0); \
    } \
} while (0)

// Phase 0: reads bf (8) + afY(=A ph1); afX (A ph0) prefetched at prev ph3.
// FIFO [afX(4), bf(8), afY(4)]: lgkm(8) -> afX+bf_s0 done; lgkm(4) -> bf_s1.
#define PHASE0(P, AFC, AFN, STG, TAILVM) do { \
    STG; \
    RD_BF(P); \
    RD_AF(AFN, 2, P); \
    LGKM(8); \
    __builtin_amdgcn_s_setprio(1); \
    MFMA8(0, AFC, 0); \
    LGKM(4); \
    MFMA8(0, AFC, 1); \
    __builtin_amdgcn_s_setprio(0); \
    TAILVM; \
    BAR; \
} while (0)

// Phases 1-3: AFC prefetched last phase; AFN = next phase's A-frags.
// FIFO [AFC(<=4), AFN(4)]: lgkm(4) -> AFC done, AFN drains under MFMA.
#define PHASEQ(Q, AFC, AFN, NI0, NPAR, STG, TAILVM) do { \
    STG; \
    RD_AF(AFN, NI0, NPAR); \
    LGKM(4); \
    __builtin_amdgcn_s_setprio(1); \
    MFMA8(Q, AFC, 0); \
    MFMA8(Q, AFC, 1); \
    __builtin_amdgcn_s_setprio(0); \
    TAILVM; \
    BAR; \
} while (0)

#define TILE_P0(kb1, kb2) do { \
    PHASE0(0, afX, afY, STG_A(kb1, 1, 1), VMW(6)); \
    PHASEQ(1, afY, afX, 4, 0, STG_B(kb2, 0, 0), VMW(4)); \
    PHASEQ(2, afX, afY, 6, 0, STG_B2A(kb2, 0), VMW(6)); \
    PHASEQ(3, afY, afX, 0, 1, NOPS, NOPS); \
} while (0)
#define TILE_P1(kb1, kb2) do { \
    PHASE0(1, afX, afY, STG_A(kb1, 0, 1), VMW(6)); \
    PHASEQ(1, afY, afX, 4, 1, STG_B(kb2, 1, 0), VMW(4)); \
    PHASEQ(2, afX, afY, 6, 1, STG_B2A(kb2, 1), VMW(6)); \
    PHASEQ(3, afY, afX, 0, 0, NOPS, NOPS); \
} while (0)

    // ---- prologue: tile 0 full + {B(1)s0, B(1)s1, A(1)s0} in flight (order
    // matters for the vmcnt FIFO), then first A-fragment prefetch.
    STG_A(0, 0, 0); STG_A(0, 0, 1); STG_B(0, 0, 0); STG_B(0, 0, 1);
    STG_B(BK, 1, 0); STG_B(BK, 1, 1); STG_A(BK, 1, 0);
    VMW(6);
    BAR;
    RD_AF(afX, 0, 0);                         // A(0) ph0 frags

    // ---- main loop: tiles 0..29
    #pragma unroll 1
    for (int it = 0; it < 15; ++it) {
        const int u0 = 2 * it;
        TILE_P0((u0 + 1) * BK, (u0 + 2) * BK);
        TILE_P1((u0 + 2) * BK, (u0 + 3) * BK);
    }

    // ---- tail: tile 30 (last DMA = A(31)s1; drain), tile 31 (compute only)
    PHASE0(0, afX, afY, STG_A(31 * BK, 1, 1), VMW(6));
    PHASEQ(1, afY, afX, 4, 0, NOPS, VMW(2));
    PHASEQ(2, afX, afY, 6, 0, NOPS, VMW(0));
    PHASEQ(3, afY, afX, 0, 1, NOPS, NOPS);
    PHASE0(1, afX, afY, NOPS, NOPS);
    PHASEQ(1, afY, afX, 4, 1, NOPS, NOPS);
    PHASEQ(2, afX, afY, 6, 1, NOPS, NOPS);
    {   // last phase: no next-tile reads
        LGKM(0);
        __builtin_amdgcn_s_setprio(1);
        MFMA8(3, afY, 0);
        MFMA8(3, afY, 1);
        __builtin_amdgcn_s_setprio(0);
    }

    // ---- epilogue
    const float stot = (__uint_as_float(*mx_bits) / 127.0f) * (*wscale_p);
    float bj[4];
    #pragma unroll
    for (int j = 0; j < 4; ++j)
        bj[j] = bias[bx * 256 + wn + j * 16 + fr];

    #pragma unroll
    for (int i = 0; i < 8; ++i) {
        int mrow = by * 256 + wm + i * 16 + kc * 4;    // + reg index rr
        #pragma unroll
        for (int rr = 0; rr < 4; ++rr) {
            float* orow = out + (size_t)(mrow + rr) * ND + bx * 256;
            #pragma unroll
            for (int j = 0; j < 4; ++j)
                orow[wn + j * 16 + fr] = (float)acc[i][j][rr] * stot + bj[j];
        }
    }
}

// ---------------------------------------------------------------- launch ----
extern "C" void kernel_launch(void* const* d_in, const int* in_sizes, int n_in,
                              void* d_out, int out_size, void* d_ws, size_t ws_size,
                              hipStream_t stream) {
    const float* x      = (const float*)d_in[0];
    const int*   wgt    = (const int*)d_in[1];     // int8 values widened to i32
    const float* wscale = (const float*)d_in[2];
    const float* bias   = (const float*)d_in[3];
    float* out = (float*)d_out;

    const int M = in_sizes[0] / KD;                // 8192

    uint8_t* ws = (uint8_t*)d_ws;
    unsigned* mx_bits = (unsigned*)ws;
    int8_t* xq = (int8_t*)(ws + 256);
    int8_t* wq = (int8_t*)(ws + 256 + (size_t)M * KD);

    const int pk_blocks = (ND * KD / 16) / 256;    // 4096
    hipMemsetAsync(mx_bits, 0, 4, stream);
    prologue_kernel<<<AB_BLOCKS + pk_blocks, 256, 0, stream>>>(
        x, mx_bits, (M * KD) / 4, wgt, wq);
    quant_x_kernel<<<AB_BLOCKS, 256, 0, stream>>>(
        x, mx_bits, xq, (M * KD) / 4);
    gemm_i8_kernel<<<dim3(ND / 256, M / 256), 512, 0, stream>>>(
        xq, wq, mx_bits, wscale, bias, out);
}